// Round 4
// baseline (147.866 us; speedup 1.0000x reference)
//
#include <hip/hip_runtime.h>
#include <hip/hip_bf16.h>
#include <stdint.h>
#include <stddef.h>

#define L_LEN 4096
#define CIN   128
#define COUT  128
#define NB    32
#define KTOT  384            // 3 * CIN, kappa = k*128 + i
#define TN    64             // h-tile per pipeline stage
#define TPB   4              // tiles per block (pipelined)
#define ROWS  (TN + 2)       // 66 (halo of 1 on each side)

typedef __bf16 bf16x8 __attribute__((ext_vector_type(8)));
typedef float  f32x4  __attribute__((ext_vector_type(4)));

__device__ __forceinline__ uint16_t f2bf(float f) {
    union { float f; uint32_t u; } v; v.f = f;
    return (uint16_t)((v.u + 0x7fffu + ((v.u >> 16) & 1u)) >> 16);  // RNE
}
__device__ __forceinline__ uint32_t pack2(float lo, float hi) {
    return (uint32_t)f2bf(lo) | ((uint32_t)f2bf(hi) << 16);
}

// ---- Prologue: combined bf16 weights in MFMA-FRAGMENT order + cbias ----
// Wc index = (((b*4 + og)*12 + t)*2 + mt)*512 + lane*8 + j
//   o   = og*32 + mt*16 + (lane&15)
//   col = t*32 + (lane>>4)*8 + j        (col = k*128 + i)
__global__ __launch_bounds__(256) void geps_combine(
    const float* __restrict__ codes, const float* __restrict__ weight,
    const float* __restrict__ Amat,  const float* __restrict__ Bmat,
    const float* __restrict__ bias,  const float* __restrict__ bias_ctx,
    uint16_t* __restrict__ Wc, float* __restrict__ cbias)
{
    int tid = blockIdx.x * 256 + threadIdx.x;
    if (tid < NB * COUT * KTOT) {
        int j    = tid & 7;
        int lane = (tid >> 3) & 63;
        int mt   = (tid >> 9) & 1;
        int tmp  = tid >> 10;
        int t    = tmp % 12;
        int bo   = tmp / 12;          // b*4 + og
        int og   = bo & 3;
        int b    = bo >> 2;
        int col  = t * 32 + (lane >> 4) * 8 + j;   // kappa = k*128 + i
        int k    = col >> 7;
        int i    = col & 127;
        int o    = og * 32 + mt * 16 + (lane & 15);
        float cw = 0.f;
        #pragma unroll
        for (int c = 0; c < 2; ++c) {
            float a = Amat[i * 6 + c * 3 + k];
            #pragma unroll
            for (int r = 0; r < 2; ++r)
                cw += a * codes[b * 4 + c * 2 + r] * Bmat[o * 6 + r * 3 + k];
        }
        float val = weight[o * 384 + i * 3 + k] + cw;   // FACTOR = 1
        Wc[tid] = f2bf(val);
    }
    if (tid < NB * COUT) {
        int b = tid >> 7, o = tid & 127;
        float cb = bias[o];
        #pragma unroll
        for (int c = 0; c < 2; ++c)
            cb += codes[b * 4 + c * 2 + c] * bias_ctx[c * 128 + o];
        cbias[tid] = cb;
    }
}

// NOTE on macro hygiene: every macro-local identifier is K_/P_/L_-prefixed
// and unique. Round 3 failed because KHALF declared `Xc = (XR)` while the
// call site passed a variable named `Xc` -> self-initialized garbage pointer.

// --- Stage HALF of a tile's input into 16 regs (issue only; no wait).
// IT=0: i-rows 0..63, IT=1: i-rows 64..127 (+ halo columns).
#define LOAD_HALF(IT, H0)                                                    \
    {                                                                        \
        int L_p4 = ((IT) << 4) + (tid >> 4);                                 \
        int L_qd = tid & 15;                                                 \
        const float* L_r0 = inb + (size_t)(4 * L_p4) * L_LEN + (H0) + 4 * L_qd; \
        st[0] = *(const float4*)(L_r0);                                      \
        st[1] = *(const float4*)(L_r0 + L_LEN);                              \
        st[2] = *(const float4*)(L_r0 + 2 * L_LEN);                          \
        st[3] = *(const float4*)(L_r0 + 3 * L_LEN);                          \
        if ((IT) && tid < 128) {                                             \
            int L_p    = tid & 63;                                           \
            int L_side = tid >> 6;                                           \
            int L_r    = L_side ? (ROWS - 1) : 0;                            \
            int L_gh   = ((H0) - 1 + L_r) & (L_LEN - 1);                     \
            hx0 = inb[(size_t)(2 * L_p) * L_LEN + L_gh];                     \
            hx1 = inb[(size_t)(2 * L_p + 1) * L_LEN + L_gh];                 \
        }                                                                    \
    }

// --- Convert staged regs to bf16, write swizzled LDS half-tile.
// (compiler inserts the vmcnt wait before first use of st/hx)
#define PACK_HALF(IT, XP)                                                    \
    {                                                                        \
        uint16_t* P_Xw = (XP);                                               \
        int P_p4 = ((IT) << 4) + (tid >> 4);                                 \
        int P_qd = tid & 15;                                                 \
        const int P_off = (4 * P_p4) & 7;                                    \
        const int P_pc  = P_p4 >> 1;                                         \
        _Pragma("unroll")                                                    \
        for (int P_j4 = 0; P_j4 < 4; ++P_j4) {                               \
            int P_r  = 1 + 4 * P_qd + P_j4;                                  \
            int P_ch = P_pc ^ (P_r & 15);                                    \
            uint2 P_w;                                                       \
            P_w.x = pack2(((const float*)&st[0])[P_j4],                      \
                          ((const float*)&st[1])[P_j4]);                     \
            P_w.y = pack2(((const float*)&st[2])[P_j4],                      \
                          ((const float*)&st[3])[P_j4]);                     \
            *(uint2*)&P_Xw[P_r * 128 + (P_ch << 3) + P_off] = P_w;           \
        }                                                                    \
        if ((IT) && tid < 128) {                                             \
            int P_p     = tid & 63;                                          \
            int P_side  = tid >> 6;                                          \
            int P_hr    = P_side ? (ROWS - 1) : 0;                           \
            int P_chunk = (P_p >> 2) ^ (P_hr & 15);                          \
            *(uint32_t*)&P_Xw[P_hr * 128 + (P_chunk << 3) + ((2 * P_p) & 7)] = \
                pack2(hx0, hx1);                                             \
        }                                                                    \
    }

// --- K-half: 6 K-steps (t = T0 .. T0+5), A-fragments streamed from
// L2-resident Wc with 1-step prefetch (16 regs, no preload panel).
#define KHALF(T0, XR)                                                        \
    {                                                                        \
        const uint16_t* K_X = (XR);                                          \
        bf16x8 K_a0 = *(const bf16x8*)(WcW + (T0) * 1024);                   \
        bf16x8 K_a1 = *(const bf16x8*)(WcW + (T0) * 1024 + 512);             \
        _Pragma("unroll")                                                    \
        for (int K_tt = 0; K_tt < 6; ++K_tt) {                               \
            const int K_t  = (T0) + K_tt;                                    \
            const int K_tn = (K_t + 1 < 12) ? (K_t + 1) : 11;                \
            bf16x8 K_n0 = *(const bf16x8*)(WcW + K_tn * 1024);               \
            bf16x8 K_n1 = *(const bf16x8*)(WcW + K_tn * 1024 + 512);         \
            const int K_k   = K_t >> 2;                                      \
            const int K_i0c = (K_t & 3) << 2;                                \
            bf16x8 K_bfv[4];                                                 \
            _Pragma("unroll")                                                \
            for (int K_nt = 0; K_nt < 4; ++K_nt) {                           \
                int K_r  = K_nt * 16 + m16 + K_k;                            \
                int K_ch = (K_i0c + q) ^ (K_r & 15);                         \
                K_bfv[K_nt] = *(const bf16x8*)&K_X[K_r * 128 + (K_ch << 3)]; \
            }                                                                \
            _Pragma("unroll")                                                \
            for (int K_nt = 0; K_nt < 4; ++K_nt) {                           \
                acc[0][K_nt] = __builtin_amdgcn_mfma_f32_16x16x32_bf16(      \
                    K_a0, K_bfv[K_nt], acc[0][K_nt], 0, 0, 0);               \
                acc[1][K_nt] = __builtin_amdgcn_mfma_f32_16x16x32_bf16(      \
                    K_a1, K_bfv[K_nt], acc[1][K_nt], 0, 0, 0);               \
            }                                                                \
            K_a0 = K_n0; K_a1 = K_n1;                                        \
        }                                                                    \
    }

// ---- Main: per-batch GEMM, M=o(128) x N=h x K=384, bf16 MFMA ----
// Intra-block pipeline over TPB=4 h-tiles, double-buffered LDS:
//   issue loads(half0, j+1) | K(t0..5, j) | pack half0 + issue loads(half1)
//   | K(t6..11, j) | stores(j) | pack half1 | barrier.
// Half-tile staging (16 regs) + L2-streamed A (16 regs) keeps arch VGPR
// ~100 (+32 AGPR acc) -> NO spill (round-2's 96-reg A-panel + 32-reg
// staging spilled to scratch: FETCH/WRITE +8 MB each, pipeline dead).
__global__ __launch_bounds__(256, 2) void geps_conv(
    const float* __restrict__ in, const uint16_t* __restrict__ Wc,
    const float* __restrict__ cbias, float* __restrict__ out)
{
    // Xt: element (r,i) at r*128 + (((i>>3)^(r&15))<<3) + (i&7)
    __shared__ uint16_t __attribute__((aligned(16))) Xt[2][ROWS * 128];
    __shared__ float cb[COUT];

    const int tid  = threadIdx.x;
    const int b    = blockIdx.y;
    const int hb   = blockIdx.x * (TN * TPB);
    const int lane = tid & 63;
    const int wid  = tid >> 6;
    const int m16  = lane & 15;
    const int q    = lane >> 4;
    const int mq   = wid * 32;           // wave's o-offset (4 waves x 32 o)

    if (tid < COUT) cb[tid] = cbias[b * COUT + tid];

    const float* inb = in + (size_t)b * CIN * L_LEN;
    // A-fragment stream base for this (b, wave): 12 steps x 2 mt x 512 bf16
    const uint16_t* WcW = Wc + (size_t)(b * 4 + wid) * 12288 + lane * 8;

    float4 st[4];
    float  hx0 = 0.f, hx1 = 0.f;
    f32x4  acc[2][4];

    // --- prologue: stage tile 0 (latency exposed once per block)
    LOAD_HALF(0, hb)
    PACK_HALF(0, &Xt[0][0])
    LOAD_HALF(1, hb)
    PACK_HALF(1, &Xt[0][0])
    __syncthreads();

    #pragma unroll 1
    for (int j = 0; j < TPB; ++j) {
        const int h0 = hb + j * TN;
        uint16_t* Xcur = &Xt[j & 1][0];
        uint16_t* Xnxt = &Xt[(j + 1) & 1][0];
        const bool pre = (j + 1 < TPB);

        // issue next tile's first-half loads NOW; land during K below
        if (pre) LOAD_HALF(0, h0 + TN)
        asm volatile("" ::: "memory");   // pin load-issue above the K-loop

        #pragma unroll
        for (int a = 0; a < 2; ++a)
            #pragma unroll
            for (int c = 0; c < 4; ++c) acc[a][c] = 0.0f;

        KHALF(0, Xcur)

        if (pre) {
            PACK_HALF(0, Xnxt)           // waits half0 loads (HBM busy time)
            LOAD_HALF(1, h0 + TN)        // issue second half
            asm volatile("" ::: "memory");
        }

        KHALF(6, Xcur)

        // --- epilogue: C/D layout col=lane&15 (h), row=(lane>>4)*4+reg (o)
        float* outb = out + (size_t)b * COUT * L_LEN + h0;
        #pragma unroll
        for (int mt = 0; mt < 2; ++mt) {
            #pragma unroll
            for (int reg = 0; reg < 4; ++reg) {
                int o = mq + mt * 16 + q * 4 + reg;
                float bv = cb[o];
                float* orow = outb + (size_t)o * L_LEN;
                #pragma unroll
                for (int nt = 0; nt < 4; ++nt)
                    __builtin_nontemporal_store(acc[mt][nt][reg] + bv,
                                                &orow[nt * 16 + m16]);
            }
        }

        if (pre) PACK_HALF(1, Xnxt)      // stores drain meanwhile
        __syncthreads();
    }
}

extern "C" void kernel_launch(void* const* d_in, const int* in_sizes, int n_in,
                              void* d_out, int out_size, void* d_ws, size_t ws_size,
                              hipStream_t stream) {
    const float* input    = (const float*)d_in[0];
    const float* codes    = (const float*)d_in[1];
    const float* weight   = (const float*)d_in[2];
    const float* Amat     = (const float*)d_in[3];
    const float* Bmat     = (const float*)d_in[4];
    const float* bias     = (const float*)d_in[5];
    const float* bias_ctx = (const float*)d_in[6];
    float* out = (float*)d_out;

    uint16_t* Wc    = (uint16_t*)d_ws;
    float*    cbias = (float*)((char*)d_ws + (size_t)NB * COUT * KTOT * 2);

    geps_combine<<<dim3((NB * COUT * KTOT) / 256), 256, 0, stream>>>(
        codes, weight, Amat, Bmat, bias, bias_ctx, Wc, cbias);
    geps_conv<<<dim3(L_LEN / (TN * TPB), NB), 256, 0, stream>>>(
        input, Wc, cbias, out);
}

// Round 5
// 144.780 us; speedup vs baseline: 1.0213x; 1.0213x over previous
//
#include <hip/hip_runtime.h>
#include <hip/hip_bf16.h>
#include <stdint.h>
#include <stddef.h>

#define L_LEN 4096
#define CIN   128
#define COUT  128
#define NB    32
#define KTOT  384            // 3 * CIN, kappa = k*128 + i
#define TN    64             // h-tile per pipeline stage
#define TPB   4              // tiles per block (pipelined)
#define ROWS  (TN + 2)       // 66 (halo of 1 on each side)

typedef __bf16 bf16x8 __attribute__((ext_vector_type(8)));
typedef float  f32x4  __attribute__((ext_vector_type(4)));

__device__ __forceinline__ uint16_t f2bf(float f) {
    union { float f; uint32_t u; } v; v.f = f;
    return (uint16_t)((v.u + 0x7fffu + ((v.u >> 16) & 1u)) >> 16);  // RNE
}
__device__ __forceinline__ uint32_t pack2(float lo, float hi) {
    return (uint32_t)f2bf(lo) | ((uint32_t)f2bf(hi) << 16);
}

// ---- Prologue: combined bf16 weights in MFMA-FRAGMENT order + cbias ----
// Wc index = (((b*4 + og)*12 + t)*2 + mt)*512 + lane*8 + j
//   o   = og*32 + mt*16 + (lane&15)
//   col = t*32 + (lane>>4)*8 + j        (col = k*128 + i)
__global__ __launch_bounds__(256) void geps_combine(
    const float* __restrict__ codes, const float* __restrict__ weight,
    const float* __restrict__ Amat,  const float* __restrict__ Bmat,
    const float* __restrict__ bias,  const float* __restrict__ bias_ctx,
    uint16_t* __restrict__ Wc, float* __restrict__ cbias)
{
    int tid = blockIdx.x * 256 + threadIdx.x;
    if (tid < NB * COUT * KTOT) {
        int j    = tid & 7;
        int lane = (tid >> 3) & 63;
        int mt   = (tid >> 9) & 1;
        int tmp  = tid >> 10;
        int t    = tmp % 12;
        int bo   = tmp / 12;          // b*4 + og
        int og   = bo & 3;
        int b    = bo >> 2;
        int col  = t * 32 + (lane >> 4) * 8 + j;   // kappa = k*128 + i
        int k    = col >> 7;
        int i    = col & 127;
        int o    = og * 32 + mt * 16 + (lane & 15);
        float cw = 0.f;
        #pragma unroll
        for (int c = 0; c < 2; ++c) {
            float a = Amat[i * 6 + c * 3 + k];
            #pragma unroll
            for (int r = 0; r < 2; ++r)
                cw += a * codes[b * 4 + c * 2 + r] * Bmat[o * 6 + r * 3 + k];
        }
        float val = weight[o * 384 + i * 3 + k] + cw;   // FACTOR = 1
        Wc[tid] = f2bf(val);
    }
    if (tid < NB * COUT) {
        int b = tid >> 7, o = tid & 127;
        float cb = bias[o];
        #pragma unroll
        for (int c = 0; c < 2; ++c)
            cb += codes[b * 4 + c * 2 + c] * bias_ctx[c * 128 + o];
        cbias[tid] = cb;
    }
}

// Macro hygiene: all macro-locals are L_/P_-prefixed (round-3 lesson).

// --- Stage HALF of a tile's input into 16 regs (issue only; no wait).
// IT=0: i-rows 0..63, IT=1: i-rows 64..127 (+ halo columns).
#define LOAD_HALF(IT, H0)                                                    \
    {                                                                        \
        int L_p4 = ((IT) << 4) + (tid >> 4);                                 \
        int L_qd = tid & 15;                                                 \
        const float* L_r0 = inb + (size_t)(4 * L_p4) * L_LEN + (H0) + 4 * L_qd; \
        st[0] = *(const float4*)(L_r0);                                      \
        st[1] = *(const float4*)(L_r0 + L_LEN);                              \
        st[2] = *(const float4*)(L_r0 + 2 * L_LEN);                          \
        st[3] = *(const float4*)(L_r0 + 3 * L_LEN);                          \
        if ((IT) && tid < 128) {                                             \
            int L_p    = tid & 63;                                           \
            int L_side = tid >> 6;                                           \
            int L_r    = L_side ? (ROWS - 1) : 0;                            \
            int L_gh   = ((H0) - 1 + L_r) & (L_LEN - 1);                     \
            hx0 = inb[(size_t)(2 * L_p) * L_LEN + L_gh];                     \
            hx1 = inb[(size_t)(2 * L_p + 1) * L_LEN + L_gh];                 \
        }                                                                    \
    }

// --- Convert staged regs to bf16, write swizzled LDS half-tile.
// (compiler inserts the vmcnt wait before first use of st/hx)
#define PACK_HALF(IT, XP)                                                    \
    {                                                                        \
        uint16_t* P_Xw = (XP);                                               \
        int P_p4 = ((IT) << 4) + (tid >> 4);                                 \
        int P_qd = tid & 15;                                                 \
        const int P_off = (4 * P_p4) & 7;                                    \
        const int P_pc  = P_p4 >> 1;                                         \
        _Pragma("unroll")                                                    \
        for (int P_j4 = 0; P_j4 < 4; ++P_j4) {                               \
            int P_r  = 1 + 4 * P_qd + P_j4;                                  \
            int P_ch = P_pc ^ (P_r & 15);                                    \
            uint2 P_w;                                                       \
            P_w.x = pack2(((const float*)&st[0])[P_j4],                      \
                          ((const float*)&st[1])[P_j4]);                     \
            P_w.y = pack2(((const float*)&st[2])[P_j4],                      \
                          ((const float*)&st[3])[P_j4]);                     \
            *(uint2*)&P_Xw[P_r * 128 + (P_ch << 3) + P_off] = P_w;           \
        }                                                                    \
        if ((IT) && tid < 128) {                                             \
            int P_p     = tid & 63;                                          \
            int P_side  = tid >> 6;                                          \
            int P_hr    = P_side ? (ROWS - 1) : 0;                           \
            int P_chunk = (P_p >> 2) ^ (P_hr & 15);                          \
            *(uint32_t*)&P_Xw[P_hr * 128 + (P_chunk << 3) + ((2 * P_p) & 7)] = \
                pack2(hx0, hx1);                                             \
        }                                                                    \
    }

// ---- Main: per-batch GEMM, M=o(128) x N=h x K=384, bf16 MFMA ----
// Intra-block pipeline over TPB=4 h-tiles, double-buffered LDS, plus:
//  * XCD-aware swizzle: XCD (d&7) owns b in [4(d&7),4(d&7)+4) -> Wc working
//    set 384 KiB per XCD L2 -> A-loads are L2 hits (round-4: +36 MB HBM
//    re-fetch from scattered-b dispatch).
//  * A-stream prefetch distance 2 (3 rolling pairs, static idx under
//    unroll) -> ~200cy of ds_read+MFMA covers L2-hit latency (round-4:
//    distance 1 stalled every K-step).
__global__ __launch_bounds__(256, 2) void geps_conv(
    const float* __restrict__ in, const uint16_t* __restrict__ Wc,
    const float* __restrict__ cbias, float* __restrict__ out)
{
    // Xt: element (r,i) at r*128 + (((i>>3)^(r&15))<<3) + (i&7)
    __shared__ uint16_t __attribute__((aligned(16))) Xt[2][ROWS * 128];
    __shared__ float cb[COUT];

    const int tid  = threadIdx.x;
    const int d    = blockIdx.x;         // 0..511
    const int b    = 4 * (d & 7) + (d >> 7);      // XCD-local b grouping
    const int hb   = ((d >> 3) & 15) * (TN * TPB);
    const int lane = tid & 63;
    const int wid  = tid >> 6;
    const int m16  = lane & 15;
    const int q    = lane >> 4;
    const int mq   = wid * 32;           // wave's o-offset (4 waves x 32 o)

    if (tid < COUT) cb[tid] = cbias[b * COUT + tid];

    const float* inb = in + (size_t)b * CIN * L_LEN;
    // A-fragment stream base for this (b, wave): 12 steps x 2 mt x 512 bf16
    const uint16_t* WcW = Wc + (size_t)(b * 4 + wid) * 12288 + lane * 8;

    float4 st[4];
    float  hx0 = 0.f, hx1 = 0.f;
    f32x4  acc[2][4];

    // --- prologue: stage tile 0 (latency exposed once per block)
    LOAD_HALF(0, hb)
    PACK_HALF(0, &Xt[0][0])
    LOAD_HALF(1, hb)
    PACK_HALF(1, &Xt[0][0])
    __syncthreads();

    #pragma unroll 1
    for (int j = 0; j < TPB; ++j) {
        const int h0 = hb + j * TN;
        uint16_t* Xcur = &Xt[j & 1][0];
        uint16_t* Xnxt = &Xt[(j + 1) & 1][0];
        const bool pre = (j + 1 < TPB);

        // issue next tile's first-half loads NOW; land during K below
        if (pre) LOAD_HALF(0, h0 + TN)
        asm volatile("" ::: "memory");   // pin load-issue above the K-loop

        #pragma unroll
        for (int a = 0; a < 2; ++a)
            #pragma unroll
            for (int c = 0; c < 4; ++c) acc[a][c] = 0.0f;

        // rolling A-fragment stream (L2-resident Wc), distance 2
        bf16x8 ar[3][2];
        ar[0][0] = *(const bf16x8*)(WcW);
        ar[0][1] = *(const bf16x8*)(WcW + 512);
        ar[1][0] = *(const bf16x8*)(WcW + 1024);
        ar[1][1] = *(const bf16x8*)(WcW + 1536);

        #pragma unroll
        for (int t = 0; t < 12; ++t) {
            if (t + 2 < 12) {
                ar[(t + 2) % 3][0] = *(const bf16x8*)(WcW + (t + 2) * 1024);
                ar[(t + 2) % 3][1] = *(const bf16x8*)(WcW + (t + 2) * 1024 + 512);
            }
            if (t == 6 && pre) {
                PACK_HALF(0, Xnxt)       // waits half0 loads (HBM-busy time)
                LOAD_HALF(1, h0 + TN)    // issue second half
                asm volatile("" ::: "memory");
            }
            const int k   = t >> 2;      // kernel tap of this K-step
            const int i0c = (t & 3) << 2;
            bf16x8 bfv[4];
            #pragma unroll
            for (int nt = 0; nt < 4; ++nt) {
                int r  = nt * 16 + m16 + k;          // Xt row = h_local + k
                int ch = (i0c + q) ^ (r & 15);
                bfv[nt] = *(const bf16x8*)&Xcur[r * 128 + (ch << 3)];
            }
            #pragma unroll
            for (int nt = 0; nt < 4; ++nt) {
                acc[0][nt] = __builtin_amdgcn_mfma_f32_16x16x32_bf16(
                    ar[t % 3][0], bfv[nt], acc[0][nt], 0, 0, 0);
                acc[1][nt] = __builtin_amdgcn_mfma_f32_16x16x32_bf16(
                    ar[t % 3][1], bfv[nt], acc[1][nt], 0, 0, 0);
            }
        }

        // --- epilogue: C/D layout col=lane&15 (h), row=(lane>>4)*4+reg (o)
        float* outb = out + (size_t)b * COUT * L_LEN + h0;
        #pragma unroll
        for (int mt = 0; mt < 2; ++mt) {
            #pragma unroll
            for (int reg = 0; reg < 4; ++reg) {
                int o = mq + mt * 16 + q * 4 + reg;
                float bv = cb[o];
                float* orow = outb + (size_t)o * L_LEN;
                #pragma unroll
                for (int nt = 0; nt < 4; ++nt)
                    __builtin_nontemporal_store(acc[mt][nt][reg] + bv,
                                                &orow[nt * 16 + m16]);
            }
        }

        if (pre) PACK_HALF(1, Xnxt)      // stores drain meanwhile
        __syncthreads();
    }
}

extern "C" void kernel_launch(void* const* d_in, const int* in_sizes, int n_in,
                              void* d_out, int out_size, void* d_ws, size_t ws_size,
                              hipStream_t stream) {
    const float* input    = (const float*)d_in[0];
    const float* codes    = (const float*)d_in[1];
    const float* weight   = (const float*)d_in[2];
    const float* Amat     = (const float*)d_in[3];
    const float* Bmat     = (const float*)d_in[4];
    const float* bias     = (const float*)d_in[5];
    const float* bias_ctx = (const float*)d_in[6];
    float* out = (float*)d_out;

    uint16_t* Wc    = (uint16_t*)d_ws;
    float*    cbias = (float*)((char*)d_ws + (size_t)NB * COUT * KTOT * 2);

    geps_combine<<<dim3((NB * COUT * KTOT) / 256), 256, 0, stream>>>(
        codes, weight, Amat, Bmat, bias, bias_ctx, Wc, cbias);
    geps_conv<<<dim3(NB * L_LEN / (TN * TPB)), 256, 0, stream>>>(
        input, Wc, cbias, out);
}

// Round 6
// 143.073 us; speedup vs baseline: 1.0335x; 1.0119x over previous
//
#include <hip/hip_runtime.h>
#include <hip/hip_bf16.h>
#include <stdint.h>
#include <stddef.h>

#define L_LEN 4096
#define CIN   128
#define COUT  128
#define NB    32
#define KTOT  384            // 3 * CIN, kappa = k*128 + i
#define TN    64             // h-tile per block
#define ROWS  (TN + 2)       // 66 (halo of 1 on each side)

typedef __bf16 bf16x8 __attribute__((ext_vector_type(8)));
typedef float  f32x4  __attribute__((ext_vector_type(4)));

__device__ __forceinline__ uint16_t f2bf(float f) {
    union { float f; uint32_t u; } v; v.f = f;
    return (uint16_t)((v.u + 0x7fffu + ((v.u >> 16) & 1u)) >> 16);  // RNE
}
__device__ __forceinline__ uint32_t pack2(float lo, float hi) {
    return (uint32_t)f2bf(lo) | ((uint32_t)f2bf(hi) << 16);
}

// ---- Prologue: combined bf16 weights in MFMA-FRAGMENT order + cbias ----
// Wc index = (((b*4 + og32)*12 + t)*2 + mt)*512 + lane*8 + j
//   o   = og32*32 + mt*16 + (lane&15)
//   col = t*32 + (lane>>4)*8 + j        (col = k*128 + i)
__global__ __launch_bounds__(256) void geps_combine(
    const float* __restrict__ codes, const float* __restrict__ weight,
    const float* __restrict__ Amat,  const float* __restrict__ Bmat,
    const float* __restrict__ bias,  const float* __restrict__ bias_ctx,
    uint16_t* __restrict__ Wc, float* __restrict__ cbias)
{
    int tid = blockIdx.x * 256 + threadIdx.x;
    if (tid < NB * COUT * KTOT) {
        int j    = tid & 7;
        int lane = (tid >> 3) & 63;
        int mt   = (tid >> 9) & 1;
        int tmp  = tid >> 10;
        int t    = tmp % 12;
        int bo   = tmp / 12;          // b*4 + og32
        int og   = bo & 3;
        int b    = bo >> 2;
        int col  = t * 32 + (lane >> 4) * 8 + j;   // kappa = k*128 + i
        int k    = col >> 7;
        int i    = col & 127;
        int o    = og * 32 + mt * 16 + (lane & 15);
        float cw = 0.f;
        #pragma unroll
        for (int c = 0; c < 2; ++c) {
            float a = Amat[i * 6 + c * 3 + k];
            #pragma unroll
            for (int r = 0; r < 2; ++r)
                cw += a * codes[b * 4 + c * 2 + r] * Bmat[o * 6 + r * 3 + k];
        }
        float val = weight[o * 384 + i * 3 + k] + cw;   // FACTOR = 1
        Wc[tid] = f2bf(val);
    }
    if (tid < NB * COUT) {
        int b = tid >> 7, o = tid & 127;
        float cb = bias[o];
        #pragma unroll
        for (int c = 0; c < 2; ++c)
            cb += codes[b * 4 + c * 2 + c] * bias_ctx[c * 128 + o];
        cbias[tid] = cb;
    }
}

// Macro hygiene: all macro-locals L_/P_-prefixed (round-3 lesson).

// --- Issue loads for QUARTER chunk C (32 i-rows x 64 h) into 4 float4 regs.
// 128 threads: i-quad p4 = C*8 + (tid>>4), h-quad qd = tid&15.
#define LOADQ(C, SB)                                                         \
    {                                                                        \
        int L_p4 = ((C) << 3) + (tid >> 4);                                  \
        int L_qd = tid & 15;                                                 \
        const float* L_r0 = inb + (size_t)(4 * L_p4) * L_LEN + h0 + 4 * L_qd; \
        (SB)[0] = *(const float4*)(L_r0);                                    \
        (SB)[1] = *(const float4*)(L_r0 + L_LEN);                            \
        (SB)[2] = *(const float4*)(L_r0 + 2 * L_LEN);                        \
        (SB)[3] = *(const float4*)(L_r0 + 3 * L_LEN);                        \
    }

// --- Convert chunk C regs to bf16, write swizzled LDS (waits via vmcnt dep).
#define PACKQ(C, SB)                                                         \
    {                                                                        \
        int P_p4 = ((C) << 3) + (tid >> 4);                                  \
        int P_qd = tid & 15;                                                 \
        const int P_off = (4 * P_p4) & 7;                                    \
        const int P_pc  = P_p4 >> 1;                                         \
        _Pragma("unroll")                                                    \
        for (int P_j4 = 0; P_j4 < 4; ++P_j4) {                               \
            int P_r  = 1 + 4 * P_qd + P_j4;                                  \
            int P_ch = P_pc ^ (P_r & 15);                                    \
            uint2 P_w;                                                       \
            P_w.x = pack2(((const float*)&(SB)[0])[P_j4],                    \
                          ((const float*)&(SB)[1])[P_j4]);                   \
            P_w.y = pack2(((const float*)&(SB)[2])[P_j4],                    \
                          ((const float*)&(SB)[3])[P_j4]);                   \
            *(uint2*)&Xt[P_r * 128 + (P_ch << 3) + P_off] = P_w;             \
        }                                                                    \
    }

// ---- Main: per-(b, h-tile, o-half) block GEMM. 128 thr = 2 waves.
// Design (round-6): many small INDEPENDENT blocks instead of pipelined
// big ones. Single-buffered 17KB LDS, exactly ONE __syncthreads, then a
// barrier-free K-loop + stores + exit. ~6 blocks/CU co-resident, mutually
// independent -> TLP hides every intra-block stall (rounds 2-5 showed
// barrier vmcnt-drains with 2 lockstep blocks/CU cap HBM at ~40%).
// Dispatch decode keeps round-5's verified XCD swizzle (FETCH 99.7->54e3):
//   xcd = d&7 (og-pair adjacent on SAME XCD -> staged input L2-hit;
//   Wc working set 384KB/XCD stays L2-resident).
__global__ __launch_bounds__(128, 3) void geps_conv(
    const float* __restrict__ in, const uint16_t* __restrict__ Wc,
    const float* __restrict__ cbias, float* __restrict__ out)
{
    // Xt: element (r,i) at r*128 + (((i>>3)^(r&15))<<3) + (i&7)
    __shared__ uint16_t __attribute__((aligned(16))) Xt[ROWS * 128];
    __shared__ float cb[64];

    const int tid  = threadIdx.x;
    const int d    = blockIdx.x;         // 0..4095
    const int xcd  = d & 7;
    const int dm   = d >> 3;             // 0..511 within XCD
    const int og   = dm & 1;             // o-half (fastest -> L2 input reuse)
    const int ht   = (dm >> 1) & 63;     // h-tile
    const int b    = 4 * xcd + (dm >> 7);
    const int h0   = ht * TN;
    const int lane = tid & 63;
    const int w    = tid >> 6;           // wave 0/1
    const int m16  = lane & 15;
    const int q    = lane >> 4;
    const int og32 = og * 2 + w;         // o-group of 32 for this wave

    if (tid < 64) cb[tid] = cbias[b * COUT + og * 64 + tid];

    const float* inb = in + (size_t)b * CIN * L_LEN;
    // A-fragment stream base for this (b, og32): 12 steps x 2 mt x 512 bf16
    const uint16_t* WcW = Wc + (size_t)(b * 4 + og32) * 12288 + lane * 8;

    // --- staging: 4 quarter chunks, 2 rolling reg sets, halo early ---
    float4 st[2][4];
    float  hx0, hx1;
    {   // halo rows r=0 (h0-1) and r=65 (h0+64), circular; 2 loads/thread
        int L_p    = tid & 63;
        int L_side = tid >> 6;
        int L_r    = L_side ? (ROWS - 1) : 0;
        int L_gh   = (h0 - 1 + L_r) & (L_LEN - 1);
        hx0 = inb[(size_t)(2 * L_p) * L_LEN + L_gh];
        hx1 = inb[(size_t)(2 * L_p + 1) * L_LEN + L_gh];
    }
    LOADQ(0, st[0])
    #pragma unroll
    for (int c = 0; c < 4; ++c) {
        if (c < 3) LOADQ(c + 1, st[(c + 1) & 1])
        asm volatile("" ::: "memory");   // keep next-chunk issue above pack
        PACKQ(c, st[c & 1])
    }
    {   // halo pack (loads long since landed)
        int P_p     = tid & 63;
        int P_side  = tid >> 6;
        int P_hr    = P_side ? (ROWS - 1) : 0;
        int P_chunk = (P_p >> 2) ^ (P_hr & 15);
        *(uint32_t*)&Xt[P_hr * 128 + (P_chunk << 3) + ((2 * P_p) & 7)] =
            pack2(hx0, hx1);
    }

    __syncthreads();                     // the ONLY barrier

    f32x4 acc[2][4];
    #pragma unroll
    for (int a = 0; a < 2; ++a)
        #pragma unroll
        for (int cc = 0; cc < 4; ++cc) acc[a][cc] = 0.0f;

    // rolling A-fragment stream (L2-resident Wc), prefetch distance 2
    bf16x8 ar[3][2];
    ar[0][0] = *(const bf16x8*)(WcW);
    ar[0][1] = *(const bf16x8*)(WcW + 512);
    ar[1][0] = *(const bf16x8*)(WcW + 1024);
    ar[1][1] = *(const bf16x8*)(WcW + 1536);

    #pragma unroll
    for (int t = 0; t < 12; ++t) {
        if (t + 2 < 12) {
            ar[(t + 2) % 3][0] = *(const bf16x8*)(WcW + (t + 2) * 1024);
            ar[(t + 2) % 3][1] = *(const bf16x8*)(WcW + (t + 2) * 1024 + 512);
        }
        const int k   = t >> 2;          // kernel tap of this K-step
        const int i0c = (t & 3) << 2;    // i-chunk base
        bf16x8 bfv[4];
        #pragma unroll
        for (int nt = 0; nt < 4; ++nt) {
            int r  = nt * 16 + m16 + k;  // Xt row = h_local + k
            int ch = (i0c + q) ^ (r & 15);
            bfv[nt] = *(const bf16x8*)&Xt[r * 128 + (ch << 3)];
        }
        #pragma unroll
        for (int nt = 0; nt < 4; ++nt) {
            acc[0][nt] = __builtin_amdgcn_mfma_f32_16x16x32_bf16(
                ar[t % 3][0], bfv[nt], acc[0][nt], 0, 0, 0);
            acc[1][nt] = __builtin_amdgcn_mfma_f32_16x16x32_bf16(
                ar[t % 3][1], bfv[nt], acc[1][nt], 0, 0, 0);
        }
    }

    // --- epilogue: C/D layout col=lane&15 (h), row=(lane>>4)*4+reg (o) ---
    float* outb = out + (size_t)b * COUT * L_LEN + h0;
    #pragma unroll
    for (int mt = 0; mt < 2; ++mt) {
        #pragma unroll
        for (int reg = 0; reg < 4; ++reg) {
            int o_loc = 32 * w + mt * 16 + q * 4 + reg;       // within og-half
            int o     = og * 64 + o_loc;                      // global o
            float bv  = cb[o_loc];
            float* orow = outb + (size_t)o * L_LEN;
            #pragma unroll
            for (int nt = 0; nt < 4; ++nt)
                __builtin_nontemporal_store(acc[mt][nt][reg] + bv,
                                            &orow[nt * 16 + m16]);
        }
    }
}

extern "C" void kernel_launch(void* const* d_in, const int* in_sizes, int n_in,
                              void* d_out, int out_size, void* d_ws, size_t ws_size,
                              hipStream_t stream) {
    const float* input    = (const float*)d_in[0];
    const float* codes    = (const float*)d_in[1];
    const float* weight   = (const float*)d_in[2];
    const float* Amat     = (const float*)d_in[3];
    const float* Bmat     = (const float*)d_in[4];
    const float* bias     = (const float*)d_in[5];
    const float* bias_ctx = (const float*)d_in[6];
    float* out = (float*)d_out;

    uint16_t* Wc    = (uint16_t*)d_ws;
    float*    cbias = (float*)((char*)d_ws + (size_t)NB * COUT * KTOT * 2);

    geps_combine<<<dim3((NB * COUT * KTOT) / 256), 256, 0, stream>>>(
        codes, weight, Amat, Bmat, bias, bias_ctx, Wc, cbias);
    // 32 b x 64 h-tiles x 2 o-halves = 4096 independent 128-thread blocks
    geps_conv<<<dim3(NB * (L_LEN / TN) * 2), 128, 0, stream>>>(
        input, Wc, cbias, out);
}